// Round 2
// baseline (545.217 us; speedup 1.0000x reference)
//
#include <hip/hip_runtime.h>
#include <math.h>

#define NRES 256
#define CDIM 8
#define HNUM 12
#define CS   384

// ===========================================================================
// Kernel 1: projections q,k,v,q_pts,k_pts,v_pts — 8 rows/block, 256 blocks.
// Unified virtual-column space over the 4 weight matrices:
//   [0,192) q | [192,576) kv | [576,720) qp | [720,1152) kvp
// ===========================================================================
__global__ __launch_bounds__(256) void proj_kernel(
    const float* __restrict__ s, const float* __restrict__ rot,
    const float* __restrict__ trans,
    const float* __restrict__ wq, const float* __restrict__ bq,
    const float* __restrict__ wkv, const float* __restrict__ bkv,
    const float* __restrict__ wqp, const float* __restrict__ bqp,
    const float* __restrict__ wkvp, const float* __restrict__ bkvp,
    float* __restrict__ qo, float* __restrict__ ko, float* __restrict__ vo,
    float* __restrict__ qpo, float* __restrict__ kpo, float* __restrict__ vpo)
{
    const int r0  = blockIdx.x * 8;       // global row base (c*256+n space)
    const int tid = threadIdx.x;
    __shared__ __align__(16) float s_sh[8*CS];   // 12 KB
    __shared__ float rawq[8*144];                // 4.5 KB
    __shared__ float rawkv[8*432];               // 13.5 KB

    for (int t = tid; t < 8*CS; t += 256) s_sh[t] = s[(size_t)r0*CS + t];
    __syncthreads();

    for (int vc0 = 0; vc0 < 1152; vc0 += 256) {
        const int vc = vc0 + tid;
        if (vc < 1152) {
            const float* wp; const float* bp; int C, lc;
            if (vc < 192)      { wp = wq;   bp = bq;   C = 192; lc = vc; }
            else if (vc < 576) { wp = wkv;  bp = bkv;  C = 384; lc = vc - 192; }
            else if (vc < 720) { wp = wqp;  bp = bqp;  C = 144; lc = vc - 576; }
            else               { wp = wkvp; bp = bkvp; C = 432; lc = vc - 720; }

            float acc[8];
            const float bb = bp[lc];
            #pragma unroll
            for (int r = 0; r < 8; ++r) acc[r] = bb;

            const float* p = wp + lc;
            for (int d = 0; d < CS; d += 4) {
                const float w0 = p[0];
                const float w1 = p[C];
                const float w2 = p[2*C];
                const float w3 = p[3*C];
                p += 4*C;
                #pragma unroll
                for (int r = 0; r < 8; ++r) {
                    const float4 s4 = *(const float4*)&s_sh[r*CS + d];
                    acc[r] = fmaf(s4.x, w0, fmaf(s4.y, w1, fmaf(s4.z, w2, fmaf(s4.w, w3, acc[r]))));
                }
            }

            if (vc < 192) {
                #pragma unroll
                for (int r = 0; r < 8; ++r) qo[(size_t)(r0+r)*192 + lc] = acc[r];
            } else if (vc < 576) {
                const int h = lc >> 5, rm = lc & 31;
                if (rm < 16) {
                    #pragma unroll
                    for (int r = 0; r < 8; ++r) ko[(size_t)(r0+r)*192 + h*16 + rm] = acc[r];
                } else {
                    #pragma unroll
                    for (int r = 0; r < 8; ++r) vo[(size_t)(r0+r)*192 + h*16 + (rm-16)] = acc[r];
                }
            } else if (vc < 720) {
                #pragma unroll
                for (int r = 0; r < 8; ++r) rawq[r*144 + lc] = acc[r];
            } else {
                #pragma unroll
                for (int r = 0; r < 8; ++r) rawkv[r*432 + lc] = acc[r];
            }
        }
    }
    __syncthreads();

    // q_pts transform: pts[p][xyz] = raw[xyz*48 + p], p = h*4+pp (48 points)
    for (int t = tid; t < 8*48; t += 256) {
        const int r = t / 48, p = t - r*48;
        const int grow = r0 + r;
        const float x = rawq[r*144 + p];
        const float y = rawq[r*144 + 48 + p];
        const float z = rawq[r*144 + 96 + p];
        const float* R = rot + (size_t)grow*9;
        const float* T = trans + (size_t)grow*3;
        qpo[(size_t)grow*144 + p*3 + 0] = R[0]*x + R[1]*y + R[2]*z + T[0];
        qpo[(size_t)grow*144 + p*3 + 1] = R[3]*x + R[4]*y + R[5]*z + T[1];
        qpo[(size_t)grow*144 + p*3 + 2] = R[6]*x + R[7]*y + R[8]*z + T[2];
    }
    // kv_pts transform: pts[p][xyz] = raw[xyz*144 + p], p = h*12+pp (144 pts)
    for (int t = tid; t < 8*144; t += 256) {
        const int r = t / 144, p = t - r*144;
        const int grow = r0 + r;
        const float x = rawkv[r*432 + p];
        const float y = rawkv[r*432 + 144 + p];
        const float z = rawkv[r*432 + 288 + p];
        const float* R = rot + (size_t)grow*9;
        const float* T = trans + (size_t)grow*3;
        const float px = R[0]*x + R[1]*y + R[2]*z + T[0];
        const float py = R[3]*x + R[4]*y + R[5]*z + T[1];
        const float pz = R[6]*x + R[7]*y + R[8]*z + T[2];
        const int h = p / 12, pp = p - h*12;
        if (pp < 4) {
            const size_t o = (size_t)grow*144 + (h*4+pp)*3;
            kpo[o+0] = px; kpo[o+1] = py; kpo[o+2] = pz;
        } else {
            const size_t o = (size_t)grow*288 + (h*8+(pp-4))*3;
            vpo[o+0] = px; vpo[o+1] = py; vpo[o+2] = pz;
        }
    }
}

// ===========================================================================
// Kernel 2: s_g = mean over C, LayerNorm, g_q/g_k projections  (per n)
// ===========================================================================
__global__ __launch_bounds__(256) void gproj_kernel(
    const float* __restrict__ s, const float* __restrict__ g_gamma,
    const float* __restrict__ g_beta,
    const float* __restrict__ wgq, const float* __restrict__ bgq,
    const float* __restrict__ wgk, const float* __restrict__ bgk,
    float* __restrict__ gqo, float* __restrict__ gko)
{
    const int n = blockIdx.x;
    const int tid = threadIdx.x;
    __shared__ float sg[CS];
    __shared__ float red[256];

    for (int d = tid; d < CS; d += 256) {
        float acc = 0.f;
        for (int c = 0; c < CDIM; ++c) acc += s[((size_t)c*NRES+n)*CS + d];
        sg[d] = acc * (1.0f/CDIM);
    }
    __syncthreads();

    float lsum = 0.f;
    for (int d = tid; d < CS; d += 256) lsum += sg[d];
    red[tid] = lsum; __syncthreads();
    for (int st = 128; st > 0; st >>= 1) { if (tid < st) red[tid] += red[tid+st]; __syncthreads(); }
    const float mean = red[0] * (1.0f/CS);
    __syncthreads();

    float lvar = 0.f;
    for (int d = tid; d < CS; d += 256) { float df = sg[d]-mean; lvar += df*df; }
    red[tid] = lvar; __syncthreads();
    for (int st = 128; st > 0; st >>= 1) { if (tid < st) red[tid] += red[tid+st]; __syncthreads(); }
    const float var = red[0] * (1.0f/CS);
    __syncthreads();

    const float inv = rsqrtf(var + 1e-5f);
    for (int d = tid; d < CS; d += 256) sg[d] = (sg[d]-mean)*inv*g_gamma[d] + g_beta[d];
    __syncthreads();

    for (int t = tid; t < 192; t += 256) {
        float aq = bgq[t], ak = bgk[t];
        for (int d = 0; d < CS; ++d) {
            aq += sg[d]*wgq[d*192 + t];
            ak += sg[d]*wgk[d*192 + t];
        }
        gqo[n*192 + t] = aq;
        gko[n*192 + t] = ak;
    }
}

// ===========================================================================
// Kernel 3: attention logits + softmax.
// Block per (c, h, i-tile of 32) = 768 blocks; k-side staged once in LDS.
// Wave w handles rows w*8..w*8+7; each lane covers 4 j's; shuffle softmax.
// ===========================================================================
__global__ __launch_bounds__(256) void attn_kernel(
    const float* __restrict__ q, const float* __restrict__ k,
    const float* __restrict__ q_pts, const float* __restrict__ k_pts,
    const float* __restrict__ g_q, const float* __restrict__ g_k,
    const float* __restrict__ trans, const float* __restrict__ mask,
    const float* __restrict__ head_weights, const float* __restrict__ wdist,
    const float* __restrict__ bdist, float* __restrict__ a_out)
{
    const int blk = blockIdx.x;
    const int iq = blk & 7;
    const int h  = (blk >> 3) % HNUM;
    const int c  = blk / (8*HNUM);
    const int i0 = iq * 32;
    const int tid = threadIdx.x;

    __shared__ __align__(16) float ksh[256*16];
    __shared__ __align__(16) float gksh[256*16];
    __shared__ __align__(16) float kpsh[256*12];
    __shared__ __align__(16) float qsh[32*16];
    __shared__ __align__(16) float gqsh[32*16];
    __shared__ __align__(16) float qpsh[32*12];
    __shared__ float tsh[256*3];
    __shared__ float msh[256];
    __shared__ float wdsh[12], bdsh[12];

    for (int t = tid; t < 4096; t += 256) {
        const int j = t >> 4, d = t & 15;
        ksh[t]  = k[((size_t)c*NRES + j)*192 + h*16 + d];
        gksh[t] = g_k[j*192 + h*16 + d];
    }
    for (int t = tid; t < 3072; t += 256) {
        const int j = t / 12, d = t - j*12;
        kpsh[t] = k_pts[((size_t)c*NRES + j)*144 + h*12 + d];
    }
    for (int t = tid; t < 512; t += 256) {
        const int i = t >> 4, d = t & 15;
        qsh[t]  = q[((size_t)c*NRES + i0 + i)*192 + h*16 + d];
        gqsh[t] = g_q[(i0 + i)*192 + h*16 + d];
    }
    for (int t = tid; t < 384; t += 256) {
        const int i = t / 12, d = t - i*12;
        qpsh[t] = q_pts[((size_t)c*NRES + i0 + i)*144 + h*12 + d];
    }
    for (int t = tid; t < 768; t += 256) tsh[t] = trans[(size_t)c*768 + t];
    if (tid < 256) msh[tid] = mask[c*NRES + tid];
    if (tid < 12) { wdsh[tid] = wdist[tid]; bdsh[tid] = bdist[tid]; }
    __syncthreads();

    const float s54   = 0.13608276348795434f;  // sqrt(1/54)
    const float scale = 0.14433756729740643f;  // sqrt(1/48)
    const float hwv = 0.5f * logf(1.0f + expf(head_weights[h])) * s54;

    const int wave = tid >> 6, lane = tid & 63;

    for (int rr = 0; rr < 8; ++rr) {
        const int il = wave*8 + rr;
        const int i  = i0 + il;
        const float4 q0 = *(const float4*)&qsh[il*16 + 0];
        const float4 q1 = *(const float4*)&qsh[il*16 + 4];
        const float4 q2 = *(const float4*)&qsh[il*16 + 8];
        const float4 q3 = *(const float4*)&qsh[il*16 + 12];
        const float4 g0 = *(const float4*)&gqsh[il*16 + 0];
        const float4 g1 = *(const float4*)&gqsh[il*16 + 4];
        const float4 g2 = *(const float4*)&gqsh[il*16 + 8];
        const float4 g3 = *(const float4*)&gqsh[il*16 + 12];
        const float4 a0 = *(const float4*)&qpsh[il*12 + 0];
        const float4 a1 = *(const float4*)&qpsh[il*12 + 4];
        const float4 a2 = *(const float4*)&qpsh[il*12 + 8];
        const float mi = msh[i];

        float lg[4];
        #pragma unroll
        for (int jj = 0; jj < 4; ++jj) {
            const int j = jj*64 + lane;
            const float4 k0 = *(const float4*)&ksh[j*16 + 0];
            const float4 k1 = *(const float4*)&ksh[j*16 + 4];
            const float4 k2 = *(const float4*)&ksh[j*16 + 8];
            const float4 k3 = *(const float4*)&ksh[j*16 + 12];
            float qk = q0.x*k0.x + q0.y*k0.y + q0.z*k0.z + q0.w*k0.w
                     + q1.x*k1.x + q1.y*k1.y + q1.z*k1.z + q1.w*k1.w
                     + q2.x*k2.x + q2.y*k2.y + q2.z*k2.z + q2.w*k2.w
                     + q3.x*k3.x + q3.y*k3.y + q3.z*k3.z + q3.w*k3.w;
            const float4 e0 = *(const float4*)&gksh[j*16 + 0];
            const float4 e1 = *(const float4*)&gksh[j*16 + 4];
            const float4 e2 = *(const float4*)&gksh[j*16 + 8];
            const float4 e3 = *(const float4*)&gksh[j*16 + 12];
            float gd = g0.x*e0.x + g0.y*e0.y + g0.z*e0.z + g0.w*e0.w
                     + g1.x*e1.x + g1.y*e1.y + g1.z*e1.z + g1.w*e1.w
                     + g2.x*e2.x + g2.y*e2.y + g2.z*e2.z + g2.w*e2.w
                     + g3.x*e3.x + g3.y*e3.y + g3.z*e3.z + g3.w*e3.w;
            const float4 c0 = *(const float4*)&kpsh[j*12 + 0];
            const float4 c1 = *(const float4*)&kpsh[j*12 + 4];
            const float4 c2 = *(const float4*)&kpsh[j*12 + 8];
            float dx, dy, dz, pt;
            dx = a0.x - c0.x; dy = a0.y - c0.y; dz = a0.z - c0.z;
            pt  = dx*dx + dy*dy + dz*dz;
            dx = a0.w - c0.w; dy = a1.x - c1.x; dz = a1.y - c1.y;
            pt += dx*dx + dy*dy + dz*dz;
            dx = a1.z - c1.z; dy = a1.w - c1.w; dz = a2.x - c2.x;
            pt += dx*dx + dy*dy + dz*dz;
            dx = a2.y - c2.y; dy = a2.z - c2.z; dz = a2.w - c2.w;
            pt += dx*dx + dy*dy + dz*dz;

            // distance bias (raw-reshape semantics)
            const int f   = h*65536 + i*256 + j;
            const int ii  = f / 3072;
            const int rem = f - ii*3072;
            const int jjx = rem / 12;
            const int ho  = rem - jjx*12;
            const float ddx = tsh[ii*3+0] - tsh[jjx*3+0];
            const float ddy = tsh[ii*3+1] - tsh[jjx*3+1];
            const float ddz = tsh[ii*3+2] - tsh[jjx*3+2];
            const float dist = sqrtf(ddx*ddx + ddy*ddy + ddz*ddz);

            lg[jj] = scale*(qk + gd) - hwv*pt
                   + 100000.0f*(mi*msh[j] - 1.0f)
                   + dist*wdsh[ho] + bdsh[ho];
        }
        float mx = fmaxf(fmaxf(lg[0], lg[1]), fmaxf(lg[2], lg[3]));
        #pragma unroll
        for (int off = 32; off > 0; off >>= 1) mx = fmaxf(mx, __shfl_xor(mx, off));
        float e[4]; float ssum = 0.f;
        #pragma unroll
        for (int jj = 0; jj < 4; ++jj) { e[jj] = __expf(lg[jj] - mx); ssum += e[jj]; }
        #pragma unroll
        for (int off = 32; off > 0; off >>= 1) ssum += __shfl_xor(ssum, off);
        const float inv = 1.0f / ssum;
        float* dst = a_out + (((size_t)c*HNUM + h)*NRES + i)*NRES;
        #pragma unroll
        for (int jj = 0; jj < 4; ++jj) dst[jj*64 + lane] = e[jj]*inv;
    }
}

// ===========================================================================
// Kernel 4a: o = a@v, o_pt = a@v_pts, inverse rigid, norms -> feat buffer.
// Block per (c, i-tile of 4) = 512 blocks; a staged transposed [j][r*12+h].
// ===========================================================================
__global__ __launch_bounds__(256) void out_feat_kernel(
    const float* __restrict__ a, const float* __restrict__ v,
    const float* __restrict__ v_pts, const float* __restrict__ rot,
    const float* __restrict__ trans, float* __restrict__ featbuf)
{
    const int blk = blockIdx.x;
    const int c  = blk >> 6;
    const int i0 = (blk & 63) * 4;
    const int tid = threadIdx.x;

    __shared__ float a_sh[256*48];     // [j][r*12+h], 48 KB
    __shared__ float feat_sh[4*576];   // 9 KB
    __shared__ float opt_sh[4*288];    // 4.5 KB

    for (int t = tid; t < 12288; t += 256) {
        const int j = t & 255, hr = t >> 8;
        const int hh = hr >> 2, r = hr & 3;
        a_sh[j*48 + r*12 + hh] = a[(((size_t)c*HNUM + hh)*NRES + (i0+r))*NRES + j];
    }
    __syncthreads();

    // o: 4 rows x 192 cols
    for (int t = tid; t < 768; t += 256) {
        const int r = t / 192, col = t - r*192;
        const int hh = col >> 4;
        float acc = 0.f;
        const float* vp = v + (size_t)c*NRES*192 + col;
        for (int j = 0; j < 256; ++j) acc += a_sh[j*48 + r*12 + hh] * vp[(size_t)j*192];
        feat_sh[r*576 + col] = acc;
    }
    // o_pt: 4 rows x 288 cols
    for (int t = tid; t < 1152; t += 256) {
        const int r = t / 288, col = t - r*288;
        const int hh = col / 24;
        float acc = 0.f;
        const float* vpp = v_pts + (size_t)c*NRES*288 + col;
        for (int j = 0; j < 256; ++j) acc += a_sh[j*48 + r*12 + hh] * vpp[(size_t)j*288];
        opt_sh[r*288 + col] = acc;
    }
    __syncthreads();

    // inverse rigid + norms; feat layout [o(192), x(96), y(96), z(96), norm(96)]
    for (int t = tid; t < 384; t += 256) {
        const int r = t / 96, p = t - r*96;
        const int grow = c*NRES + i0 + r;
        const float x = opt_sh[r*288 + p*3+0] - trans[(size_t)grow*3+0];
        const float y = opt_sh[r*288 + p*3+1] - trans[(size_t)grow*3+1];
        const float z = opt_sh[r*288 + p*3+2] - trans[(size_t)grow*3+2];
        const float* R = rot + (size_t)grow*9;
        const float rx = R[0]*x + R[3]*y + R[6]*z;
        const float ry = R[1]*x + R[4]*y + R[7]*z;
        const float rz = R[2]*x + R[5]*y + R[8]*z;
        feat_sh[r*576 + 192 + p] = rx;
        feat_sh[r*576 + 288 + p] = ry;
        feat_sh[r*576 + 384 + p] = rz;
        feat_sh[r*576 + 480 + p] = sqrtf(rx*rx + ry*ry + rz*rz + 1e-8f);
    }
    __syncthreads();

    float* dst = featbuf + (size_t)(c*NRES + i0)*576;
    for (int t = tid; t < 2304; t += 256) dst[t] = feat_sh[t];
}

// ===========================================================================
// Kernel 4b: out0 = feat @ wout + bout  (2048x576 @ 576x384), 8 rows/block
// ===========================================================================
__global__ __launch_bounds__(256) void out_gemm_kernel(
    const float* __restrict__ featbuf, const float* __restrict__ wout,
    const float* __restrict__ bout, float* __restrict__ out0)
{
    const int r0 = blockIdx.x * 8;
    const int tid = threadIdx.x;
    __shared__ __align__(16) float fsh[8*576];   // 18 KB

    for (int t = tid; t < 8*576; t += 256) fsh[t] = featbuf[(size_t)r0*576 + t];
    __syncthreads();

    for (int t0 = 0; t0 < 384; t0 += 256) {
        const int t = t0 + tid;
        if (t < 384) {
            float acc[8];
            const float bb = bout[t];
            #pragma unroll
            for (int r = 0; r < 8; ++r) acc[r] = bb;
            const float* p = wout + t;
            for (int d = 0; d < 576; d += 4) {
                const float w0 = p[0];
                const float w1 = p[384];
                const float w2 = p[768];
                const float w3 = p[1152];
                p += 1536;
                #pragma unroll
                for (int r = 0; r < 8; ++r) {
                    const float4 s4 = *(const float4*)&fsh[r*576 + d];
                    acc[r] = fmaf(s4.x, w0, fmaf(s4.y, w1, fmaf(s4.z, w2, fmaf(s4.w, w3, acc[r]))));
                }
            }
            #pragma unroll
            for (int r = 0; r < 8; ++r) out0[(size_t)(r0+r)*CS + t] = acc[r];
        }
    }
}

// ===========================================================================
extern "C" void kernel_launch(void* const* d_in, const int* in_sizes, int n_in,
                              void* d_out, int out_size, void* d_ws, size_t ws_size,
                              hipStream_t stream)
{
    const float* s     = (const float*)d_in[0];
    const float* rot   = (const float*)d_in[2];
    const float* trans = (const float*)d_in[3];
    const float* mask  = (const float*)d_in[4];
    const float* wq    = (const float*)d_in[5];
    const float* bq    = (const float*)d_in[6];
    const float* wkv   = (const float*)d_in[7];
    const float* bkv   = (const float*)d_in[8];
    const float* g_gamma = (const float*)d_in[9];
    const float* g_beta  = (const float*)d_in[10];
    const float* wgq   = (const float*)d_in[11];
    const float* bgq   = (const float*)d_in[12];
    const float* wgk   = (const float*)d_in[13];
    const float* bgk   = (const float*)d_in[14];
    const float* wqp   = (const float*)d_in[15];
    const float* bqp   = (const float*)d_in[16];
    const float* wkvp  = (const float*)d_in[17];
    const float* bkvp  = (const float*)d_in[18];
    const float* head_weights = (const float*)d_in[19];
    const float* wdist = (const float*)d_in[20];
    const float* bdist = (const float*)d_in[21];
    const float* wout  = (const float*)d_in[22];
    const float* bout  = (const float*)d_in[23];

    float* ws      = (float*)d_ws;
    float* q_buf   = ws + 0;          // 393216
    float* qp_buf  = ws + 393216;     // 294912
    float* kp_buf  = ws + 688128;     // 294912
    float* gq_buf  = ws + 983040;     // 49152
    float* gk_buf  = ws + 1032192;    // 49152
    float* k_buf   = ws + 1081344;    // 393216
    float* v_buf   = ws + 1474560;    // 393216
    float* vp_buf  = ws + 1867776;    // 589824  (total 2457600)
    float* featbuf = ws + 0;          // 1179648, overlays q/qp/kp/gq/gk/k[0:98304]
                                      // (all dead after attn_kernel)

    float* out0  = (float*)d_out;       // (1,8,256,384) = 786432
    float* a_out = out0 + 786432;       // (1,8,12,256,256) = 6291456

    proj_kernel<<<256, 256, 0, stream>>>(s, rot, trans, wq, bq, wkv, bkv,
                                         wqp, bqp, wkvp, bkvp,
                                         q_buf, k_buf, v_buf, qp_buf, kp_buf, vp_buf);
    gproj_kernel<<<256, 256, 0, stream>>>(s, g_gamma, g_beta, wgq, bgq, wgk, bgk,
                                          gq_buf, gk_buf);
    attn_kernel<<<768, 256, 0, stream>>>(q_buf, k_buf, qp_buf, kp_buf, gq_buf, gk_buf,
                                         trans, mask, head_weights, wdist, bdist, a_out);
    out_feat_kernel<<<512, 256, 0, stream>>>(a_out, v_buf, vp_buf, rot, trans, featbuf);
    out_gemm_kernel<<<256, 256, 0, stream>>>(featbuf, wout, bout, out0);
}

// Round 3
// 334.516 us; speedup vs baseline: 1.6299x; 1.6299x over previous
//
#include <hip/hip_runtime.h>
#include <math.h>

#define NRES 256
#define CDIM 8
#define HNUM 12
#define CS   384

// ===========================================================================
// Kernel 1: unified projection GEMM  C[2048][1152] = s[2048][384] @ W + b
// virtual cols: [0,192) q | [192,576) kv | [576,720) qp-raw | [720,1152) kvp-raw
// Tiling: 32 rows x 128 cols per block; grid = 64 x 9 = 576 blocks.
// Wave owns 8 rows; lane owns 2 cols; acc[8][2] in registers.
// Raw point cols go to rawp (overlaid on a_out region); transformed later.
// ===========================================================================
__global__ __launch_bounds__(256) void proj_kernel(
    const float* __restrict__ s,
    const float* __restrict__ wq, const float* __restrict__ bq,
    const float* __restrict__ wkv, const float* __restrict__ bkv,
    const float* __restrict__ wqp, const float* __restrict__ bqp,
    const float* __restrict__ wkvp, const float* __restrict__ bkvp,
    float* __restrict__ qo, float* __restrict__ ko, float* __restrict__ vo,
    float* __restrict__ rawp)
{
    const int blk = blockIdx.x;
    const int rt = blk / 9, ct = blk - rt*9;
    const int r0 = rt * 32;
    const int tid = threadIdx.x;
    const int wave = tid >> 6, lane = tid & 63;

    __shared__ __align__(16) float s_sh[32*CS];   // 48 KB

    // stage 32 rows of s (coalesced float4)
    {
        const float4* sg = (const float4*)(s + (size_t)r0*CS);
        float4* sp = (float4*)s_sh;
        for (int t = tid; t < 32*CS/4; t += 256) sp[t] = sg[t];
    }

    // resolve the two columns this thread owns
    float acc[8][2];
    const float* p0; const float* p1;
    int C0, C1, vc0, vc1;
    {
        const int c = ct*128 + lane;
        vc0 = c;
        const float* w; const float* b; int C, lc;
        if (c < 192)      { w = wq;   b = bq;   C = 192; lc = c; }
        else if (c < 576) { w = wkv;  b = bkv;  C = 384; lc = c - 192; }
        else if (c < 720) { w = wqp;  b = bqp;  C = 144; lc = c - 576; }
        else              { w = wkvp; b = bkvp; C = 432; lc = c - 720; }
        p0 = w + lc; C0 = C;
        const float bb = b[lc];
        #pragma unroll
        for (int r = 0; r < 8; ++r) acc[r][0] = bb;
    }
    {
        const int c = ct*128 + lane + 64;
        vc1 = c;
        const float* w; const float* b; int C, lc;
        if (c < 192)      { w = wq;   b = bq;   C = 192; lc = c; }
        else if (c < 576) { w = wkv;  b = bkv;  C = 384; lc = c - 192; }
        else if (c < 720) { w = wqp;  b = bqp;  C = 144; lc = c - 576; }
        else              { w = wkvp; b = bkvp; C = 432; lc = c - 720; }
        p1 = w + lc; C1 = C;
        const float bb = b[lc];
        #pragma unroll
        for (int r = 0; r < 8; ++r) acc[r][1] = bb;
    }
    __syncthreads();

    const float* srow = &s_sh[wave*8*CS];
    for (int d = 0; d < CS; d += 4) {
        const float w00 = p0[0], w01 = p0[C0], w02 = p0[2*C0], w03 = p0[3*C0];
        const float w10 = p1[0], w11 = p1[C1], w12 = p1[2*C1], w13 = p1[3*C1];
        p0 += 4*C0; p1 += 4*C1;
        #pragma unroll
        for (int r = 0; r < 8; ++r) {
            const float4 sv = *(const float4*)&srow[r*CS + d];
            acc[r][0] = fmaf(sv.x,w00,fmaf(sv.y,w01,fmaf(sv.z,w02,fmaf(sv.w,w03,acc[r][0]))));
            acc[r][1] = fmaf(sv.x,w10,fmaf(sv.y,w11,fmaf(sv.z,w12,fmaf(sv.w,w13,acc[r][1]))));
        }
    }

    #pragma unroll
    for (int n = 0; n < 2; ++n) {
        const int c = (n == 0) ? vc0 : vc1;
        #pragma unroll
        for (int r = 0; r < 8; ++r) {
            const int grow = r0 + wave*8 + r;
            const float val = acc[r][n];
            if (c < 192) {
                qo[(size_t)grow*192 + c] = val;
            } else if (c < 576) {
                const int lc = c - 192, h = lc >> 5, rm = lc & 31;
                if (rm < 16) ko[(size_t)grow*192 + h*16 + rm] = val;
                else         vo[(size_t)grow*192 + h*16 + rm - 16] = val;
            } else {
                rawp[(size_t)grow*576 + (c - 576)] = val;   // qp:[0,144) kvp:[144,576)
            }
        }
    }
}

// ===========================================================================
// Kernel 1b: rigid transform of raw points -> q_pts / k_pts / v_pts
// 2048 rows x 192 points; grid = 1536 x 256
// ===========================================================================
__global__ __launch_bounds__(256) void pt_transform_kernel(
    const float* __restrict__ rawp, const float* __restrict__ rot,
    const float* __restrict__ trans,
    float* __restrict__ qpo, float* __restrict__ kpo, float* __restrict__ vpo)
{
    const int t = blockIdx.x*256 + threadIdx.x;   // < 2048*192
    const int row = t / 192;
    const int p = t - row*192;
    const float* R = rot + (size_t)row*9;
    const float* T = trans + (size_t)row*3;
    const float* base = rawp + (size_t)row*576;
    float x, y, z;
    if (p < 48) { x = base[p];       y = base[48+p];  z = base[96+p]; }
    else { const int pk = p-48; x = base[144+pk]; y = base[288+pk]; z = base[432+pk]; }
    const float px = R[0]*x + R[1]*y + R[2]*z + T[0];
    const float py = R[3]*x + R[4]*y + R[5]*z + T[1];
    const float pz = R[6]*x + R[7]*y + R[8]*z + T[2];
    if (p < 48) {
        float* o = qpo + (size_t)row*144 + p*3;
        o[0]=px; o[1]=py; o[2]=pz;
    } else {
        const int pk = p-48, h = pk/12, pp = pk - h*12;
        if (pp < 4) { float* o = kpo + (size_t)row*144 + (h*4+pp)*3;     o[0]=px; o[1]=py; o[2]=pz; }
        else        { float* o = vpo + (size_t)row*288 + (h*8+(pp-4))*3; o[0]=px; o[1]=py; o[2]=pz; }
    }
}

// ===========================================================================
// Kernel 2: s_g = mean over C, LayerNorm, g_q/g_k projections  (per n)
// ===========================================================================
__global__ __launch_bounds__(256) void gproj_kernel(
    const float* __restrict__ s, const float* __restrict__ g_gamma,
    const float* __restrict__ g_beta,
    const float* __restrict__ wgq, const float* __restrict__ bgq,
    const float* __restrict__ wgk, const float* __restrict__ bgk,
    float* __restrict__ gqo, float* __restrict__ gko)
{
    const int n = blockIdx.x;
    const int tid = threadIdx.x;
    __shared__ float sg[CS];
    __shared__ float red[256];

    for (int d = tid; d < CS; d += 256) {
        float acc = 0.f;
        for (int c = 0; c < CDIM; ++c) acc += s[((size_t)c*NRES+n)*CS + d];
        sg[d] = acc * (1.0f/CDIM);
    }
    __syncthreads();

    float lsum = 0.f;
    for (int d = tid; d < CS; d += 256) lsum += sg[d];
    red[tid] = lsum; __syncthreads();
    for (int st = 128; st > 0; st >>= 1) { if (tid < st) red[tid] += red[tid+st]; __syncthreads(); }
    const float mean = red[0] * (1.0f/CS);
    __syncthreads();

    float lvar = 0.f;
    for (int d = tid; d < CS; d += 256) { float df = sg[d]-mean; lvar += df*df; }
    red[tid] = lvar; __syncthreads();
    for (int st = 128; st > 0; st >>= 1) { if (tid < st) red[tid] += red[tid+st]; __syncthreads(); }
    const float var = red[0] * (1.0f/CS);
    __syncthreads();

    const float inv = rsqrtf(var + 1e-5f);
    for (int d = tid; d < CS; d += 256) sg[d] = (sg[d]-mean)*inv*g_gamma[d] + g_beta[d];
    __syncthreads();

    for (int t = tid; t < 192; t += 256) {
        float aq = bgq[t], ak = bgk[t];
        for (int d = 0; d < CS; ++d) {
            aq += sg[d]*wgq[d*192 + t];
            ak += sg[d]*wgk[d*192 + t];
        }
        gqo[n*192 + t] = aq;
        gko[n*192 + t] = ak;
    }
}

// ===========================================================================
// Kernel 3: attention logits + softmax.
// Block per (c, h, i-tile of 32) = 768 blocks; k-side staged once in LDS.
// ===========================================================================
__global__ __launch_bounds__(256) void attn_kernel(
    const float* __restrict__ q, const float* __restrict__ k,
    const float* __restrict__ q_pts, const float* __restrict__ k_pts,
    const float* __restrict__ g_q, const float* __restrict__ g_k,
    const float* __restrict__ trans, const float* __restrict__ mask,
    const float* __restrict__ head_weights, const float* __restrict__ wdist,
    const float* __restrict__ bdist, float* __restrict__ a_out)
{
    const int blk = blockIdx.x;
    const int iq = blk & 7;
    const int h  = (blk >> 3) % HNUM;
    const int c  = blk / (8*HNUM);
    const int i0 = iq * 32;
    const int tid = threadIdx.x;

    __shared__ __align__(16) float ksh[256*16];
    __shared__ __align__(16) float gksh[256*16];
    __shared__ __align__(16) float kpsh[256*12];
    __shared__ __align__(16) float qsh[32*16];
    __shared__ __align__(16) float gqsh[32*16];
    __shared__ __align__(16) float qpsh[32*12];
    __shared__ float tsh[256*3];
    __shared__ float msh[256];
    __shared__ float wdsh[12], bdsh[12];

    for (int t = tid; t < 4096; t += 256) {
        const int j = t >> 4, d = t & 15;
        ksh[t]  = k[((size_t)c*NRES + j)*192 + h*16 + d];
        gksh[t] = g_k[j*192 + h*16 + d];
    }
    for (int t = tid; t < 3072; t += 256) {
        const int j = t / 12, d = t - j*12;
        kpsh[t] = k_pts[((size_t)c*NRES + j)*144 + h*12 + d];
    }
    for (int t = tid; t < 512; t += 256) {
        const int i = t >> 4, d = t & 15;
        qsh[t]  = q[((size_t)c*NRES + i0 + i)*192 + h*16 + d];
        gqsh[t] = g_q[(i0 + i)*192 + h*16 + d];
    }
    for (int t = tid; t < 384; t += 256) {
        const int i = t / 12, d = t - i*12;
        qpsh[t] = q_pts[((size_t)c*NRES + i0 + i)*144 + h*12 + d];
    }
    for (int t = tid; t < 768; t += 256) tsh[t] = trans[(size_t)c*768 + t];
    if (tid < 256) msh[tid] = mask[c*NRES + tid];
    if (tid < 12) { wdsh[tid] = wdist[tid]; bdsh[tid] = bdist[tid]; }
    __syncthreads();

    const float s54   = 0.13608276348795434f;  // sqrt(1/54)
    const float scale = 0.14433756729740643f;  // sqrt(1/48)
    const float hwv = 0.5f * logf(1.0f + expf(head_weights[h])) * s54;

    const int wave = tid >> 6, lane = tid & 63;

    for (int rr = 0; rr < 8; ++rr) {
        const int il = wave*8 + rr;
        const int i  = i0 + il;
        const float4 q0 = *(const float4*)&qsh[il*16 + 0];
        const float4 q1 = *(const float4*)&qsh[il*16 + 4];
        const float4 q2 = *(const float4*)&qsh[il*16 + 8];
        const float4 q3 = *(const float4*)&qsh[il*16 + 12];
        const float4 g0 = *(const float4*)&gqsh[il*16 + 0];
        const float4 g1 = *(const float4*)&gqsh[il*16 + 4];
        const float4 g2 = *(const float4*)&gqsh[il*16 + 8];
        const float4 g3 = *(const float4*)&gqsh[il*16 + 12];
        const float4 a0 = *(const float4*)&qpsh[il*12 + 0];
        const float4 a1 = *(const float4*)&qpsh[il*12 + 4];
        const float4 a2 = *(const float4*)&qpsh[il*12 + 8];
        const float mi = msh[i];

        float lg[4];
        #pragma unroll
        for (int jj = 0; jj < 4; ++jj) {
            const int j = jj*64 + lane;
            const float4 k0 = *(const float4*)&ksh[j*16 + 0];
            const float4 k1 = *(const float4*)&ksh[j*16 + 4];
            const float4 k2 = *(const float4*)&ksh[j*16 + 8];
            const float4 k3 = *(const float4*)&ksh[j*16 + 12];
            float qk = q0.x*k0.x + q0.y*k0.y + q0.z*k0.z + q0.w*k0.w
                     + q1.x*k1.x + q1.y*k1.y + q1.z*k1.z + q1.w*k1.w
                     + q2.x*k2.x + q2.y*k2.y + q2.z*k2.z + q2.w*k2.w
                     + q3.x*k3.x + q3.y*k3.y + q3.z*k3.z + q3.w*k3.w;
            const float4 e0 = *(const float4*)&gksh[j*16 + 0];
            const float4 e1 = *(const float4*)&gksh[j*16 + 4];
            const float4 e2 = *(const float4*)&gksh[j*16 + 8];
            const float4 e3 = *(const float4*)&gksh[j*16 + 12];
            float gd = g0.x*e0.x + g0.y*e0.y + g0.z*e0.z + g0.w*e0.w
                     + g1.x*e1.x + g1.y*e1.y + g1.z*e1.z + g1.w*e1.w
                     + g2.x*e2.x + g2.y*e2.y + g2.z*e2.z + g2.w*e2.w
                     + g3.x*e3.x + g3.y*e3.y + g3.z*e3.z + g3.w*e3.w;
            const float4 c0 = *(const float4*)&kpsh[j*12 + 0];
            const float4 c1 = *(const float4*)&kpsh[j*12 + 4];
            const float4 c2 = *(const float4*)&kpsh[j*12 + 8];
            float dx, dy, dz, pt;
            dx = a0.x - c0.x; dy = a0.y - c0.y; dz = a0.z - c0.z;
            pt  = dx*dx + dy*dy + dz*dz;
            dx = a0.w - c0.w; dy = a1.x - c1.x; dz = a1.y - c1.y;
            pt += dx*dx + dy*dy + dz*dz;
            dx = a1.z - c1.z; dy = a1.w - c1.w; dz = a2.x - c2.x;
            pt += dx*dx + dy*dy + dz*dz;
            dx = a2.y - c2.y; dy = a2.z - c2.z; dz = a2.w - c2.w;
            pt += dx*dx + dy*dy + dz*dz;

            const int f   = h*65536 + i*256 + j;
            const int ii  = f / 3072;
            const int rem = f - ii*3072;
            const int jjx = rem / 12;
            const int ho  = rem - jjx*12;
            const float ddx = tsh[ii*3+0] - tsh[jjx*3+0];
            const float ddy = tsh[ii*3+1] - tsh[jjx*3+1];
            const float ddz = tsh[ii*3+2] - tsh[jjx*3+2];
            const float dist = sqrtf(ddx*ddx + ddy*ddy + ddz*ddz);

            lg[jj] = scale*(qk + gd) - hwv*pt
                   + 100000.0f*(mi*msh[j] - 1.0f)
                   + dist*wdsh[ho] + bdsh[ho];
        }
        float mx = fmaxf(fmaxf(lg[0], lg[1]), fmaxf(lg[2], lg[3]));
        #pragma unroll
        for (int off = 32; off > 0; off >>= 1) mx = fmaxf(mx, __shfl_xor(mx, off));
        float e[4]; float ssum = 0.f;
        #pragma unroll
        for (int jj = 0; jj < 4; ++jj) { e[jj] = __expf(lg[jj] - mx); ssum += e[jj]; }
        #pragma unroll
        for (int off = 32; off > 0; off >>= 1) ssum += __shfl_xor(ssum, off);
        const float inv = 1.0f / ssum;
        float* dst = a_out + (((size_t)c*HNUM + h)*NRES + i)*NRES;
        #pragma unroll
        for (int jj = 0; jj < 4; ++jj) dst[jj*64 + lane] = e[jj]*inv;
    }
}

// ===========================================================================
// Kernel 4a: o = a@v, o_pt = a@v_pts, inverse rigid, norms -> feat buffer.
// ===========================================================================
__global__ __launch_bounds__(256) void out_feat_kernel(
    const float* __restrict__ a, const float* __restrict__ v,
    const float* __restrict__ v_pts, const float* __restrict__ rot,
    const float* __restrict__ trans, float* __restrict__ featbuf)
{
    const int blk = blockIdx.x;
    const int c  = blk >> 6;
    const int i0 = (blk & 63) * 4;
    const int tid = threadIdx.x;

    __shared__ float a_sh[256*48];
    __shared__ float feat_sh[4*576];
    __shared__ float opt_sh[4*288];

    for (int t = tid; t < 12288; t += 256) {
        const int j = t & 255, hr = t >> 8;
        const int hh = hr >> 2, r = hr & 3;
        a_sh[j*48 + r*12 + hh] = a[(((size_t)c*HNUM + hh)*NRES + (i0+r))*NRES + j];
    }
    __syncthreads();

    for (int t = tid; t < 768; t += 256) {
        const int r = t / 192, col = t - r*192;
        const int hh = col >> 4;
        float acc = 0.f;
        const float* vp = v + (size_t)c*NRES*192 + col;
        for (int j = 0; j < 256; ++j) acc += a_sh[j*48 + r*12 + hh] * vp[(size_t)j*192];
        feat_sh[r*576 + col] = acc;
    }
    for (int t = tid; t < 1152; t += 256) {
        const int r = t / 288, col = t - r*288;
        const int hh = col / 24;
        float acc = 0.f;
        const float* vpp = v_pts + (size_t)c*NRES*288 + col;
        for (int j = 0; j < 256; ++j) acc += a_sh[j*48 + r*12 + hh] * vpp[(size_t)j*288];
        opt_sh[r*288 + col] = acc;
    }
    __syncthreads();

    for (int t = tid; t < 384; t += 256) {
        const int r = t / 96, p = t - r*96;
        const int grow = c*NRES + i0 + r;
        const float x = opt_sh[r*288 + p*3+0] - trans[(size_t)grow*3+0];
        const float y = opt_sh[r*288 + p*3+1] - trans[(size_t)grow*3+1];
        const float z = opt_sh[r*288 + p*3+2] - trans[(size_t)grow*3+2];
        const float* R = rot + (size_t)grow*9;
        const float rx = R[0]*x + R[3]*y + R[6]*z;
        const float ry = R[1]*x + R[4]*y + R[7]*z;
        const float rz = R[2]*x + R[5]*y + R[8]*z;
        feat_sh[r*576 + 192 + p] = rx;
        feat_sh[r*576 + 288 + p] = ry;
        feat_sh[r*576 + 384 + p] = rz;
        feat_sh[r*576 + 480 + p] = sqrtf(rx*rx + ry*ry + rz*rz + 1e-8f);
    }
    __syncthreads();

    float* dst = featbuf + (size_t)(c*NRES + i0)*576;
    for (int t = tid; t < 2304; t += 256) dst[t] = feat_sh[t];
}

// ===========================================================================
// Kernel 4b: out0 = feat @ wout + bout  (2048x576 @ 576x384)
// Tiling: 16 rows x 128 cols; grid = 128 x 3 = 384 blocks; wave=4 rows, lane=2 cols
// ===========================================================================
__global__ __launch_bounds__(256) void out_gemm_kernel(
    const float* __restrict__ featbuf, const float* __restrict__ wout,
    const float* __restrict__ bout, float* __restrict__ out0)
{
    const int blk = blockIdx.x;
    const int rt = blk / 3, ct = blk - rt*3;
    const int r0 = rt * 16;
    const int tid = threadIdx.x;
    const int wave = tid >> 6, lane = tid & 63;

    __shared__ __align__(16) float fsh[16*576];   // 36 KB

    {
        const float4* fg = (const float4*)(featbuf + (size_t)r0*576);
        float4* fp = (float4*)fsh;
        for (int t = tid; t < 16*576/4; t += 256) fp[t] = fg[t];
    }

    const int c0 = ct*128 + lane;
    const int c1 = c0 + 64;
    float acc[4][2];
    {
        const float b0 = bout[c0], b1 = bout[c1];
        #pragma unroll
        for (int r = 0; r < 4; ++r) { acc[r][0] = b0; acc[r][1] = b1; }
    }
    __syncthreads();

    const float* p0 = wout + c0;
    const float* p1 = wout + c1;
    const float* frow = &fsh[wave*4*576];
    for (int d = 0; d < 576; d += 4) {
        const float w00 = p0[0], w01 = p0[384], w02 = p0[768], w03 = p0[1152];
        const float w10 = p1[0], w11 = p1[384], w12 = p1[768], w13 = p1[1152];
        p0 += 1536; p1 += 1536;
        #pragma unroll
        for (int r = 0; r < 4; ++r) {
            const float4 sv = *(const float4*)&frow[r*576 + d];
            acc[r][0] = fmaf(sv.x,w00,fmaf(sv.y,w01,fmaf(sv.z,w02,fmaf(sv.w,w03,acc[r][0]))));
            acc[r][1] = fmaf(sv.x,w10,fmaf(sv.y,w11,fmaf(sv.z,w12,fmaf(sv.w,w13,acc[r][1]))));
        }
    }

    #pragma unroll
    for (int r = 0; r < 4; ++r) {
        const int grow = r0 + wave*4 + r;
        out0[(size_t)grow*CS + c0] = acc[r][0];
        out0[(size_t)grow*CS + c1] = acc[r][1];
    }
}

// ===========================================================================
extern "C" void kernel_launch(void* const* d_in, const int* in_sizes, int n_in,
                              void* d_out, int out_size, void* d_ws, size_t ws_size,
                              hipStream_t stream)
{
    const float* s     = (const float*)d_in[0];
    const float* rot   = (const float*)d_in[2];
    const float* trans = (const float*)d_in[3];
    const float* mask  = (const float*)d_in[4];
    const float* wq    = (const float*)d_in[5];
    const float* bq    = (const float*)d_in[6];
    const float* wkv   = (const float*)d_in[7];
    const float* bkv   = (const float*)d_in[8];
    const float* g_gamma = (const float*)d_in[9];
    const float* g_beta  = (const float*)d_in[10];
    const float* wgq   = (const float*)d_in[11];
    const float* bgq   = (const float*)d_in[12];
    const float* wgk   = (const float*)d_in[13];
    const float* bgk   = (const float*)d_in[14];
    const float* wqp   = (const float*)d_in[15];
    const float* bqp   = (const float*)d_in[16];
    const float* wkvp  = (const float*)d_in[17];
    const float* bkvp  = (const float*)d_in[18];
    const float* head_weights = (const float*)d_in[19];
    const float* wdist = (const float*)d_in[20];
    const float* bdist = (const float*)d_in[21];
    const float* wout  = (const float*)d_in[22];
    const float* bout  = (const float*)d_in[23];

    float* ws      = (float*)d_ws;
    float* q_buf   = ws + 0;          // 393216
    float* qp_buf  = ws + 393216;     // 294912
    float* kp_buf  = ws + 688128;     // 294912
    float* gq_buf  = ws + 983040;     // 49152
    float* gk_buf  = ws + 1032192;    // 49152
    float* k_buf   = ws + 1081344;    // 393216
    float* v_buf   = ws + 1474560;    // 393216
    float* vp_buf  = ws + 1867776;    // 589824 (total 2457600)
    float* featbuf = ws + 0;          // 1179648, overlays q/qp/kp/gq/gk/k-head
                                      // (all dead once out_feat runs)

    float* out0  = (float*)d_out;       // 786432
    float* a_out = out0 + 786432;       // 6291456
    float* rawp  = a_out;               // 1179648 raw point projections,
                                        // overlaid on a_out (dead until attn)

    proj_kernel<<<576, 256, 0, stream>>>(s, wq, bq, wkv, bkv, wqp, bqp, wkvp, bkvp,
                                         q_buf, k_buf, v_buf, rawp);
    pt_transform_kernel<<<1536, 256, 0, stream>>>(rawp, rot, trans,
                                                  qp_buf, kp_buf, vp_buf);
    gproj_kernel<<<256, 256, 0, stream>>>(s, g_gamma, g_beta, wgq, bgq, wgk, bgk,
                                          gq_buf, gk_buf);
    attn_kernel<<<768, 256, 0, stream>>>(q_buf, k_buf, qp_buf, kp_buf, gq_buf, gk_buf,
                                         trans, mask, head_weights, wdist, bdist, a_out);
    out_feat_kernel<<<512, 256, 0, stream>>>(a_out, v_buf, vp_buf, rot, trans, featbuf);
    out_gemm_kernel<<<384, 256, 0, stream>>>(featbuf, wout, bout, out0);
}